// Round 14
// baseline (296.533 us; speedup 1.0000x reference)
//
#include <hip/hip_runtime.h>
#include <hip/hip_bf16.h>
#include <stdint.h>

// D-MPNN encoder, fused per-molecule kernel (R13 + manual SW-pipelined k-loops).
// Graph facts: ring molecules, 24 atoms / 48 bonds each; other(b) in-molecule;
// a2b[v]={2v-1,2v}; molecule m owns atoms 1+24m.., bonds 1+48m..
// Ledger (counter-verified):
//   R4/R5/R7/R8/R9: reg working set over cap -> scratch spills.
//   R6/R10: full-unroll k-loops -> 208 arch -> 1 wave/SIMD, 334 us.
//   R11: LDS W-ring neutral (its 143KB LDS forced 1-block residency - invalid test).
//   R12: unroll-1 k-loops -> 104 VGPR -> 2 blocks/CU, 251 us.
//   R13: inp->acc-init + ping-pong + native cvt -> 227 us. MfmaUtil 22 /
//        VALU 34 / occ 22% -> per-k-step latency exposure is the residual.
//   R14 (this): distance-1 register SW pipeline (unroll-2 ping-pong, static
//        names): load k+1 while MFMA k. Live ~230 regs <= 256 -> keep 2 blocks.

typedef __attribute__((ext_vector_type(8))) short s8v;
typedef __attribute__((ext_vector_type(4))) float f4v;

__device__ __forceinline__ float u2f(unsigned int u){
  union { unsigned int i; float f; } v; v.i = u; return v.f;
}
__device__ __forceinline__ unsigned short f2bf(float f){
  union { __hip_bfloat16 b; unsigned short u; } cv;
  cv.b = __float2bfloat16(f);           // hardware RNE
  return cv.u;
}
__device__ __forceinline__ float bf2f(unsigned short u){
  return u2f(((unsigned int)u)<<16);
}

// Build MFMA B-fragment layout: frag[ks][nf][lane][8],
//   element = W[k = ks*32 + (lane>>4)*8 + j][n = nf*16 + (lane&15)] (0 outside)
// remap=1 (W_o with concat padding): k<133 -> k, 133..143 -> 0, 144..443 -> k-11, else 0.
__global__ void conv_w_k(const float* __restrict__ W, unsigned short* __restrict__ frag,
                         int NS, int K0, int remap)
{
  int id = blockIdx.x*256 + threadIdx.x;
  int total = NS*20*64;
  if (id>=total) return;
  int lane = id & 63;
  int fid = id >> 6;
  int nf = fid % 20, ks = fid / 20;
  int n = nf*16 + (lane & 15);
  int kb = ks*32 + (lane>>4)*8;
  unsigned short o[8];
#pragma unroll
  for (int j=0;j<8;j++){
    int k = kb + j;
    int ksrc;
    if (remap){
      if (k < 133) ksrc = k;
      else if (k < 144) ksrc = -1;
      else if (k < 444) ksrc = k - 11;
      else ksrc = -1;
    } else {
      ksrc = (k < K0) ? k : -1;
    }
    float v = (ksrc >= 0 && n < 300) ? W[(size_t)ksrc*300 + n] : 0.f;
    o[j] = f2bf(v);
  }
  *(s8v*)(frag + (size_t)id*8) = *(const s8v*)o;
}

// Fused per-molecule MPNN. 256 threads = 4 waves (1M x 4N); per wave all M rows
// x 80 cols (5 nf). LDS: ping-pong B0/B1 [48][320] bf16 (chunk^=row&7 swizzle)
// + oth[48]. B0 doubles as fb staging and hid f32; B1 doubles as ain.
// inp residual in 30 packed-bf16 VGPRs, folded into acc init.
__global__ __launch_bounds__(256) void mpnn_fused(
    const float* __restrict__ f_atoms, const float* __restrict__ f_bonds,
    const int* __restrict__ a2b, const int* __restrict__ b2a,
    const int* __restrict__ b2revb,
    const unsigned short* __restrict__ wif, const unsigned short* __restrict__ whf,
    const unsigned short* __restrict__ wof, const float* __restrict__ b_o,
    float* __restrict__ out)
{
  __shared__ unsigned char L[61632];
  unsigned short* B0 = (unsigned short*)L;              // [48][320] swizzled
  unsigned short* B1 = (unsigned short*)(L + 30720);    // [48][320] swizzled
  int* oth = (int*)(L + 61440);                         // [48]
  unsigned short* ain = B1;                             // [32][448] swizzled (after iters)
  float* hid = (float*)B0;                              // [24][300] f32 (after ain staging)

  const int tid  = threadIdx.x;
  const int lane = tid & 63;
  const int w    = tid >> 6;
  const int lrow = lane & 15;
  const int kq   = lane >> 4;
  const int wn0  = w*5;
  const int blk  = blockIdx.x;
  const int gb0  = 48*blk + 1;   // first global bond of this molecule
  const int ga0  = 24*blk + 1;   // first global atom

  // ---- per-bond "other" index (local) ----
  if (tid < 48){
    int gb = gb0 + tid;
    int u = b2a[gb];
    oth[tid] = a2b[2*u] + a2b[2*u+1] - b2revb[gb] - gb0;
  }
  // ---- stage f_bonds -> bf16 LDS B0 [48][24 chunks], swizzled ----
  for (int c = tid; c < 48*24; c += 256){
    int row = c/24, ch = c - row*24;
    const float* sp = f_bonds + (size_t)(gb0+row)*147;
    unsigned short o[8];
#pragma unroll
    for (int j=0;j<8;j++){
      int col = ch*8+j;
      o[j] = f2bf(col < 147 ? sp[col] : 0.f);
    }
    *(s8v*)(B0 + (size_t)row*192 + (((ch^(row&7))<<3))) = *(const s8v*)o;
  }
  __syncthreads();

  f4v acc[3][5];
  s8v bA[5], bB[5], aA[3], aB[3];

#define LDB(dst, WB, KS) { const unsigned short* wp_ = (WB) + ((size_t)((KS)*20 + wn0)*64 + lane)*8; \
  _Pragma("unroll") for (int n_=0;n_<5;n_++) dst[n_] = *(const s8v*)(wp_ + n_*512); }
#define LDA3(dst, SRC, STRIDE, R0,R1,R2, KS) { \
  dst[0] = *(const s8v*)((SRC) + (size_t)(R0)*(STRIDE) + ((((KS)*4+kq)^((R0)&7))<<3)); \
  dst[1] = *(const s8v*)((SRC) + (size_t)(R1)*(STRIDE) + ((((KS)*4+kq)^((R1)&7))<<3)); \
  dst[2] = *(const s8v*)((SRC) + (size_t)(R2)*(STRIDE) + ((((KS)*4+kq)^((R2)&7))<<3)); }
#define FMA3(aa, bb) { _Pragma("unroll") for (int n_=0;n_<5;n_++) \
  _Pragma("unroll") for (int mf_=0;mf_<3;mf_++) \
    acc[mf_][n_] = __builtin_amdgcn_mfma_f32_16x16x32_bf16(aa[mf_], bb[n_], acc[mf_][n_], 0,0,0); }

  // ---- GEMM0: inp = fb @ W_i  (K=192, NS=6), fb in B0, pipelined ----
#pragma unroll
  for (int mf=0;mf<3;mf++)
#pragma unroll
    for (int n=0;n<5;n++) acc[mf][n] = (f4v){0.f,0.f,0.f,0.f};

  {
    const int r0 = lrow, r1 = 16+lrow, r2 = 32+lrow;
    LDB(bA, wif, 0); LDA3(aA, B0, 192, r0,r1,r2, 0);
#pragma unroll 1
    for (int ks=0; ks<6; ks+=2){
      LDB(bB, wif, ks+1); LDA3(aB, B0, 192, r0,r1,r2, ks+1);
      FMA3(aA, bA);
      if (ks+2 < 6){ LDB(bA, wif, ks+2); LDA3(aA, B0, 192, r0,r1,r2, ks+2); }
      FMA3(aB, bB);
    }
  }

  // ---- inp -> packed-bf16 regs; msg0 = relu(inp) -> B1 ----
  unsigned int inpP0[3][5], inpP1[3][5];   // [r0|r1<<16], [r2|r3<<16]
#pragma unroll
  for (int mf=0;mf<3;mf++){
#pragma unroll
    for (int n=0;n<5;n++){
      inpP0[mf][n] = (unsigned)f2bf(acc[mf][n][0]) | ((unsigned)f2bf(acc[mf][n][1])<<16);
      inpP1[mf][n] = (unsigned)f2bf(acc[mf][n][2]) | ((unsigned)f2bf(acc[mf][n][3])<<16);
      int col = (wn0+n)*16 + lrow;
#pragma unroll
      for (int r=0;r<4;r++){
        int row = mf*16 + kq*4 + r;
        float v = acc[mf][n][r];
        B1[(size_t)row*320 + (((col>>3)^(row&7))<<3) + (col&7)] = f2bf(v>0.f ? v : 0.f);
      }
    }
  }
  __syncthreads();

  const int g0 = oth[lrow], g1 = oth[16+lrow], g2 = oth[32+lrow];

  // ---- 5 message-update iterations, ping-pong B1->B0->..., pipelined ----
#pragma unroll 1
  for (int it=0; it<5; ++it){
    const unsigned short* rd = (it&1) ? B0 : B1;
    unsigned short*       wr = (it&1) ? B1 : B0;
    // acc init = inp residual
#pragma unroll
    for (int mf=0;mf<3;mf++)
#pragma unroll
      for (int n=0;n<5;n++){
        unsigned int p0 = inpP0[mf][n], p1 = inpP1[mf][n];
        acc[mf][n][0] = u2f(p0<<16);
        acc[mf][n][1] = u2f(p0 & 0xffff0000u);
        acc[mf][n][2] = u2f(p1<<16);
        acc[mf][n][3] = u2f(p1 & 0xffff0000u);
      }

    LDB(bA, whf, 0); LDA3(aA, rd, 320, g0,g1,g2, 0);
#pragma unroll 1
    for (int ks=0; ks<10; ks+=2){
      LDB(bB, whf, ks+1); LDA3(aB, rd, 320, g0,g1,g2, ks+1);
      FMA3(aA, bA);
      if (ks+2 < 10){ LDB(bA, whf, ks+2); LDA3(aA, rd, 320, g0,g1,g2, ks+2); }
      FMA3(aB, bB);
    }
    // epilogue: msg_new = relu(acc) -> other buffer
#pragma unroll
    for (int mf=0;mf<3;mf++){
#pragma unroll
      for (int n=0;n<5;n++){
        int col = (wn0+n)*16 + lrow;
#pragma unroll
        for (int r=0;r<4;r++){
          int row = mf*16 + kq*4 + r;
          float v = acc[mf][n][r];
          wr[(size_t)row*320 + (((col>>3)^(row&7))<<3) + (col&7)] = f2bf(v>0.f ? v : 0.f);
        }
      }
    }
    __syncthreads();
  }
  // final msg in B0 (it=4 wrote B0)

  // ---- stage a_in = [f_atoms | 0 | amsg | 0] into B1-as-ain [32][56 ch] ----
  for (int c = tid; c < 32*56; c += 256){
    int row = c/56, ch = c - row*56;
    unsigned short o[8];
#pragma unroll
    for (int j=0;j<8;j++) o[j] = 0;
    if (row < 24){
      if (ch < 17){
        const float* ap = f_atoms + (size_t)(ga0+row)*133;
#pragma unroll
        for (int j=0;j<8;j++){
          int col = ch*8+j;
          o[j] = f2bf(col < 133 ? ap[col] : 0.f);
        }
      } else if (ch >= 18){
        int q = ch - 18;
        int r2 = 2*row, r3 = 2*row+1;
        s8v a = *(const s8v*)(B0 + (size_t)r2*320 + ((q^(r2&7))<<3));
        s8v b = *(const s8v*)(B0 + (size_t)r3*320 + ((q^(r3&7))<<3));
#pragma unroll
        for (int j=0;j<8;j++)
          o[j] = f2bf(bf2f((unsigned short)a[j]) + bf2f((unsigned short)b[j]));
      }
    }
    *(s8v*)(ain + (size_t)row*448 + ((ch^(row&7))<<3)) = *(const s8v*)o;
  }
  __syncthreads();

  // ---- GEMM3: hid = relu(a_in @ W_o + b_o) (K=448, NS=14, M=32 incl pad), pipelined ----
  f4v acc2[2][5];
#pragma unroll
  for (int mf=0;mf<2;mf++)
#pragma unroll
    for (int n=0;n<5;n++) acc2[mf][n] = (f4v){0.f,0.f,0.f,0.f};

#define LDA2(dst, KS) { \
  dst[0] = *(const s8v*)(ain + (size_t)(lrow)*448 + ((((KS)*4+kq)^(lrow&7))<<3)); \
  dst[1] = *(const s8v*)(ain + (size_t)(16+lrow)*448 + ((((KS)*4+kq)^((16+lrow)&7))<<3)); }
#define FMA2(aa, bb) { _Pragma("unroll") for (int n_=0;n_<5;n_++) \
  _Pragma("unroll") for (int mf_=0;mf_<2;mf_++) \
    acc2[mf_][n_] = __builtin_amdgcn_mfma_f32_16x16x32_bf16(aa[mf_], bb[n_], acc2[mf_][n_], 0,0,0); }

  {
    LDB(bA, wof, 0); LDA2(aA, 0);
#pragma unroll 1
    for (int ks=0; ks<14; ks+=2){
      LDB(bB, wof, ks+1); LDA2(aB, ks+1);
      FMA2(aA, bA);
      if (ks+2 < 14){ LDB(bA, wof, ks+2); LDA2(aA, ks+2); }
      FMA2(aB, bB);
    }
  }
  // B0 fully consumed -> hid f32
#pragma unroll
  for (int mf=0;mf<2;mf++){
#pragma unroll
    for (int n=0;n<5;n++){
      int col = (wn0+n)*16 + lrow;
      if (col < 300){
        float bo = b_o[col];
#pragma unroll
        for (int r=0;r<4;r++){
          int row = mf*16 + kq*4 + r;
          if (row < 24){
            float v = acc2[mf][n][r] + bo;
            hid[row*300 + col] = v>0.f ? v : 0.f;
          }
        }
      }
    }
  }
  __syncthreads();

  // ---- per-molecule mean over 24 atoms ----
  for (int c = tid; c < 300; c += 256){
    float s = 0.f;
#pragma unroll
    for (int a=0;a<24;a++) s += hid[a*300 + c];
    out[(size_t)blk*300 + c] = s * (1.0f/24.0f);
  }
#undef LDB
#undef LDA3
#undef FMA3
#undef LDA2
#undef FMA2
}

extern "C" void kernel_launch(void* const* d_in, const int* in_sizes, int n_in,
                              void* d_out, int out_size, void* d_ws, size_t ws_size,
                              hipStream_t stream)
{
  const float* f_atoms = (const float*)d_in[0];
  const float* f_bonds = (const float*)d_in[1];
  const int* a2b    = (const int*)d_in[2];
  const int* b2a    = (const int*)d_in[4];
  const int* b2revb = (const int*)d_in[5];
  const float* W_i = (const float*)d_in[8];
  const float* W_h = (const float*)d_in[9];
  const float* W_o = (const float*)d_in[10];
  const float* b_o = (const float*)d_in[11];

  const int NA   = in_sizes[2] / 2;   // 49153 (incl dummy atom 0)
  const int MOLS = (NA - 1) / 24;     // 2048

  // workspace: W fragment buffers only (~600 KB)
  unsigned short* wif = (unsigned short*)d_ws;
  unsigned short* whf = wif + (size_t)6*20*64*8;
  unsigned short* wof = whf + (size_t)10*20*64*8;
  (void)ws_size; (void)n_in; (void)out_size;

  hipLaunchKernelGGL(conv_w_k, dim3((6*20*64+255)/256),  dim3(256), 0, stream, W_i, wif, 6, 147, 0);
  hipLaunchKernelGGL(conv_w_k, dim3((10*20*64+255)/256), dim3(256), 0, stream, W_h, whf, 10, 300, 0);
  hipLaunchKernelGGL(conv_w_k, dim3((14*20*64+255)/256), dim3(256), 0, stream, W_o, wof, 14, 433, 1);

  hipLaunchKernelGGL(mpnn_fused, dim3(MOLS), dim3(256), 0, stream,
                     f_atoms, f_bonds, a2b, b2a, b2revb,
                     wif, whf, wof, b_o, (float*)d_out);
}

// Round 15
// 211.966 us; speedup vs baseline: 1.3990x; 1.3990x over previous
//
#include <hip/hip_runtime.h>
#include <hip/hip_bf16.h>
#include <stdint.h>

// D-MPNN encoder, fused per-molecule kernel (R13 base + zero-step skip +
// vectorized feature staging). R14's SW-pipeline reverted (reg cliff).
// Graph facts: ring molecules, 24 atoms / 48 bonds each; other(b) in-molecule;
// a2b[v]={2v-1,2v}; molecule m owns atoms 1+24m.., bonds 1+48m..
// Ledger (counter-verified):
//   R4-R9: reg working set over cap -> scratch spills (0.3-1.7 GB).
//   R6/R10: full-unroll k-loops -> 208 VGPR -> 1 wave/SIMD, 334 us.
//   R12: unroll-1 k-loops -> 104 VGPR -> 2 blocks/CU, 251 us.
//   R13: inp->acc-init + ping-pong + native cvt -> 227 us (VGPR 128, occ 22%).
//   R14: dist-1 reg pipeline -> VGPR 148 -> occupancy HALVED (1 blk/CU), 297 us.
//   EMPIRICAL RULE: VGPR_Count <= 128 <=> 2 blocks/CU. R13 sits at the edge;
//   all further changes must be register-neutral.
//   R15 (this): GEMM0 6->5 k-steps (K_real=147<=160, step 5 was all-zero);
//   f_bonds/f_atoms staged with packed aligned(4) float4 loads, guards only
//   on the single partial chunk.

typedef __attribute__((ext_vector_type(8))) short s8v;
typedef __attribute__((ext_vector_type(4))) float f4v;
typedef float f4u __attribute__((ext_vector_type(4), aligned(4)));  // unaligned-ok vec load

__device__ __forceinline__ float u2f(unsigned int u){
  union { unsigned int i; float f; } v; v.i = u; return v.f;
}
__device__ __forceinline__ unsigned short f2bf(float f){
  union { __hip_bfloat16 b; unsigned short u; } cv;
  cv.b = __float2bfloat16(f);           // hardware RNE
  return cv.u;
}
__device__ __forceinline__ float bf2f(unsigned short u){
  return u2f(((unsigned int)u)<<16);
}

// Build MFMA B-fragment layout: frag[ks][nf][lane][8],
//   element = W[k = ks*32 + (lane>>4)*8 + j][n = nf*16 + (lane&15)] (0 outside)
// remap=1 (W_o with concat padding): k<133 -> k, 133..143 -> 0, 144..443 -> k-11, else 0.
__global__ void conv_w_k(const float* __restrict__ W, unsigned short* __restrict__ frag,
                         int NS, int K0, int remap)
{
  int id = blockIdx.x*256 + threadIdx.x;
  int total = NS*20*64;
  if (id>=total) return;
  int lane = id & 63;
  int fid = id >> 6;
  int nf = fid % 20, ks = fid / 20;
  int n = nf*16 + (lane & 15);
  int kb = ks*32 + (lane>>4)*8;
  unsigned short o[8];
#pragma unroll
  for (int j=0;j<8;j++){
    int k = kb + j;
    int ksrc;
    if (remap){
      if (k < 133) ksrc = k;
      else if (k < 144) ksrc = -1;
      else if (k < 444) ksrc = k - 11;
      else ksrc = -1;
    } else {
      ksrc = (k < K0) ? k : -1;
    }
    float v = (ksrc >= 0 && n < 300) ? W[(size_t)ksrc*300 + n] : 0.f;
    o[j] = f2bf(v);
  }
  *(s8v*)(frag + (size_t)id*8) = *(const s8v*)o;
}

// Fused per-molecule MPNN. 256 threads = 4 waves (1M x 4N); per wave all M rows
// x 80 cols (5 nf). LDS: ping-pong B0/B1 [48][320] bf16 (chunk^=row&7 swizzle)
// + oth[48]. B0 doubles as fb staging [48][192] and hid f32; B1 doubles as ain.
// inp residual in 30 packed-bf16 VGPRs, folded into acc init.
__global__ __launch_bounds__(256) void mpnn_fused(
    const float* __restrict__ f_atoms, const float* __restrict__ f_bonds,
    const int* __restrict__ a2b, const int* __restrict__ b2a,
    const int* __restrict__ b2revb,
    const unsigned short* __restrict__ wif, const unsigned short* __restrict__ whf,
    const unsigned short* __restrict__ wof, const float* __restrict__ b_o,
    float* __restrict__ out)
{
  __shared__ unsigned char L[61632];
  unsigned short* B0 = (unsigned short*)L;              // [48][320] swizzled
  unsigned short* B1 = (unsigned short*)(L + 30720);    // [48][320] swizzled
  int* oth = (int*)(L + 61440);                         // [48]
  unsigned short* ain = B1;                             // [32][448] swizzled (after iters)
  float* hid = (float*)B0;                              // [24][300] f32 (after ain staging)

  const int tid  = threadIdx.x;
  const int lane = tid & 63;
  const int w    = tid >> 6;
  const int lrow = lane & 15;
  const int kq   = lane >> 4;
  const int wn0  = w*5;
  const int blk  = blockIdx.x;
  const int gb0  = 48*blk + 1;   // first global bond of this molecule
  const int ga0  = 24*blk + 1;   // first global atom

  // ---- per-bond "other" index (local) ----
  if (tid < 48){
    int gb = gb0 + tid;
    int u = b2a[gb];
    oth[tid] = a2b[2*u] + a2b[2*u+1] - b2revb[gb] - gb0;
  }
  // ---- stage f_bonds -> bf16 LDS B0 [48][24 chunks], swizzled ----
  // chunks 0-17 are fully inside the 147-float row (vector loads, no guard);
  // chunk 18 partial (cols 144-146); chunks 19-23 zero.
  for (int c = tid; c < 48*24; c += 256){
    int row = c/24, ch = c - row*24;
    const float* sp = f_bonds + (size_t)(gb0+row)*147 + ch*8;
    unsigned short o[8];
    if (ch < 18){
      f4u v0 = *(const f4u*)(sp);
      f4u v1 = *(const f4u*)(sp+4);
#pragma unroll
      for (int j=0;j<4;j++){ o[j] = f2bf(v0[j]); o[4+j] = f2bf(v1[j]); }
    } else if (ch == 18){
#pragma unroll
      for (int j=0;j<8;j++) o[j] = f2bf((144+j) < 147 ? sp[j] : 0.f);
    } else {
#pragma unroll
      for (int j=0;j<8;j++) o[j] = 0;
    }
    *(s8v*)(B0 + (size_t)row*192 + (((ch^(row&7))<<3))) = *(const s8v*)o;
  }
  __syncthreads();

  // ---- GEMM0: inp = fb @ W_i  (K_real=147 -> 5 k-steps of 32), fb in B0 ----
  f4v acc[3][5];
#pragma unroll
  for (int mf=0;mf<3;mf++)
#pragma unroll
    for (int n=0;n<5;n++) acc[mf][n] = (f4v){0.f,0.f,0.f,0.f};

#pragma unroll 1
  for (int ks=0; ks<5; ks++){
    const unsigned short* wp = wif + ((size_t)(ks*20 + wn0)*64 + lane)*8;
    s8v bfr[5];
#pragma unroll
    for (int n=0;n<5;n++) bfr[n] = *(const s8v*)(wp + n*512);
    s8v af[3];
#pragma unroll
    for (int mf=0;mf<3;mf++){
      int row = mf*16 + lrow;
      af[mf] = *(const s8v*)(B0 + (size_t)row*192 + (((ks*4+kq)^(row&7))<<3));
    }
#pragma unroll
    for (int n=0;n<5;n++)
#pragma unroll
      for (int mf=0;mf<3;mf++)
        acc[mf][n] = __builtin_amdgcn_mfma_f32_16x16x32_bf16(af[mf], bfr[n], acc[mf][n], 0,0,0);
  }

  // ---- inp -> packed-bf16 regs; msg0 = relu(inp) -> B1 ----
  unsigned int inpP0[3][5], inpP1[3][5];   // [r0|r1<<16], [r2|r3<<16]
#pragma unroll
  for (int mf=0;mf<3;mf++){
#pragma unroll
    for (int n=0;n<5;n++){
      inpP0[mf][n] = (unsigned)f2bf(acc[mf][n][0]) | ((unsigned)f2bf(acc[mf][n][1])<<16);
      inpP1[mf][n] = (unsigned)f2bf(acc[mf][n][2]) | ((unsigned)f2bf(acc[mf][n][3])<<16);
      int col = (wn0+n)*16 + lrow;
#pragma unroll
      for (int r=0;r<4;r++){
        int row = mf*16 + kq*4 + r;
        float v = acc[mf][n][r];
        B1[(size_t)row*320 + (((col>>3)^(row&7))<<3) + (col&7)] = f2bf(v>0.f ? v : 0.f);
      }
    }
  }
  __syncthreads();

  const int g0 = oth[lrow], g1 = oth[16+lrow], g2 = oth[32+lrow];

  // ---- 5 message-update iterations, ping-pong B1->B0->B1->B0->B1->B0 ----
#pragma unroll 1
  for (int it=0; it<5; ++it){
    const unsigned short* rd = (it&1) ? B0 : B1;
    unsigned short*       wr = (it&1) ? B1 : B0;
    // acc init = inp residual
#pragma unroll
    for (int mf=0;mf<3;mf++)
#pragma unroll
      for (int n=0;n<5;n++){
        unsigned int p0 = inpP0[mf][n], p1 = inpP1[mf][n];
        acc[mf][n][0] = u2f(p0<<16);
        acc[mf][n][1] = u2f(p0 & 0xffff0000u);
        acc[mf][n][2] = u2f(p1<<16);
        acc[mf][n][3] = u2f(p1 & 0xffff0000u);
      }

#pragma unroll 1
    for (int ks=0; ks<10; ks++){
      const unsigned short* wp = whf + ((size_t)(ks*20 + wn0)*64 + lane)*8;
      s8v bfr[5];
#pragma unroll
      for (int n=0;n<5;n++) bfr[n] = *(const s8v*)(wp + n*512);
      s8v af[3];
      af[0] = *(const s8v*)(rd + (size_t)g0*320 + (((ks*4+kq)^(g0&7))<<3));
      af[1] = *(const s8v*)(rd + (size_t)g1*320 + (((ks*4+kq)^(g1&7))<<3));
      af[2] = *(const s8v*)(rd + (size_t)g2*320 + (((ks*4+kq)^(g2&7))<<3));
#pragma unroll
      for (int n=0;n<5;n++)
#pragma unroll
        for (int mf=0;mf<3;mf++)
          acc[mf][n] = __builtin_amdgcn_mfma_f32_16x16x32_bf16(af[mf], bfr[n], acc[mf][n], 0,0,0);
    }
    // epilogue: msg_new = relu(acc) -> other buffer
#pragma unroll
    for (int mf=0;mf<3;mf++){
#pragma unroll
      for (int n=0;n<5;n++){
        int col = (wn0+n)*16 + lrow;
#pragma unroll
        for (int r=0;r<4;r++){
          int row = mf*16 + kq*4 + r;
          float v = acc[mf][n][r];
          wr[(size_t)row*320 + (((col>>3)^(row&7))<<3) + (col&7)] = f2bf(v>0.f ? v : 0.f);
        }
      }
    }
    __syncthreads();
  }
  // final msg in B0 (it=4 wrote B0)

  // ---- stage a_in = [f_atoms | 0 | amsg | 0] into B1-as-ain [32][56 ch] ----
  // f_atoms rows are 133 floats: chunks 0-15 full (vector), chunk 16 partial.
  for (int c = tid; c < 32*56; c += 256){
    int row = c/56, ch = c - row*56;
    unsigned short o[8];
#pragma unroll
    for (int j=0;j<8;j++) o[j] = 0;
    if (row < 24){
      if (ch < 16){
        const float* ap = f_atoms + (size_t)(ga0+row)*133 + ch*8;
        f4u v0 = *(const f4u*)(ap);
        f4u v1 = *(const f4u*)(ap+4);
#pragma unroll
        for (int j=0;j<4;j++){ o[j] = f2bf(v0[j]); o[4+j] = f2bf(v1[j]); }
      } else if (ch == 16){
        const float* ap = f_atoms + (size_t)(ga0+row)*133 + 128;
#pragma unroll
        for (int j=0;j<8;j++) o[j] = f2bf((128+j) < 133 ? ap[j] : 0.f);
      } else if (ch >= 18){
        int q = ch - 18;
        int r2 = 2*row, r3 = 2*row+1;
        s8v a = *(const s8v*)(B0 + (size_t)r2*320 + ((q^(r2&7))<<3));
        s8v b = *(const s8v*)(B0 + (size_t)r3*320 + ((q^(r3&7))<<3));
#pragma unroll
        for (int j=0;j<8;j++)
          o[j] = f2bf(bf2f((unsigned short)a[j]) + bf2f((unsigned short)b[j]));
      }
    }
    *(s8v*)(ain + (size_t)row*448 + ((ch^(row&7))<<3)) = *(const s8v*)o;
  }
  __syncthreads();

  // ---- GEMM3: hid = relu(a_in @ W_o + b_o)  (K=448, 14 k-steps, M=32 incl pad) ----
  f4v acc2[2][5];
#pragma unroll
  for (int mf=0;mf<2;mf++)
#pragma unroll
    for (int n=0;n<5;n++) acc2[mf][n] = (f4v){0.f,0.f,0.f,0.f};

#pragma unroll 1
  for (int ks=0; ks<14; ks++){
    const unsigned short* wp = wof + ((size_t)(ks*20 + wn0)*64 + lane)*8;
    s8v bfr[5];
#pragma unroll
    for (int n=0;n<5;n++) bfr[n] = *(const s8v*)(wp + n*512);
    s8v af[2];
#pragma unroll
    for (int mf=0;mf<2;mf++){
      int row = mf*16 + lrow;
      af[mf] = *(const s8v*)(ain + (size_t)row*448 + (((ks*4+kq)^(row&7))<<3));
    }
#pragma unroll
    for (int n=0;n<5;n++)
#pragma unroll
      for (int mf=0;mf<2;mf++)
        acc2[mf][n] = __builtin_amdgcn_mfma_f32_16x16x32_bf16(af[mf], bfr[n], acc2[mf][n], 0,0,0);
  }
  // B0 fully consumed -> hid f32
#pragma unroll
  for (int mf=0;mf<2;mf++){
#pragma unroll
    for (int n=0;n<5;n++){
      int col = (wn0+n)*16 + lrow;
      if (col < 300){
        float bo = b_o[col];
#pragma unroll
        for (int r=0;r<4;r++){
          int row = mf*16 + kq*4 + r;
          if (row < 24){
            float v = acc2[mf][n][r] + bo;
            hid[row*300 + col] = v>0.f ? v : 0.f;
          }
        }
      }
    }
  }
  __syncthreads();

  // ---- per-molecule mean over 24 atoms ----
  for (int c = tid; c < 300; c += 256){
    float s = 0.f;
#pragma unroll
    for (int a=0;a<24;a++) s += hid[a*300 + c];
    out[(size_t)blk*300 + c] = s * (1.0f/24.0f);
  }
}

extern "C" void kernel_launch(void* const* d_in, const int* in_sizes, int n_in,
                              void* d_out, int out_size, void* d_ws, size_t ws_size,
                              hipStream_t stream)
{
  const float* f_atoms = (const float*)d_in[0];
  const float* f_bonds = (const float*)d_in[1];
  const int* a2b    = (const int*)d_in[2];
  const int* b2a    = (const int*)d_in[4];
  const int* b2revb = (const int*)d_in[5];
  const float* W_i = (const float*)d_in[8];
  const float* W_h = (const float*)d_in[9];
  const float* W_o = (const float*)d_in[10];
  const float* b_o = (const float*)d_in[11];

  const int NA   = in_sizes[2] / 2;   // 49153 (incl dummy atom 0)
  const int MOLS = (NA - 1) / 24;     // 2048

  // workspace: W fragment buffers only (~600 KB)
  unsigned short* wif = (unsigned short*)d_ws;               // 5 k-steps
  unsigned short* whf = wif + (size_t)5*20*64*8;             // 10 k-steps
  unsigned short* wof = whf + (size_t)10*20*64*8;            // 14 k-steps
  (void)ws_size; (void)n_in; (void)out_size;

  hipLaunchKernelGGL(conv_w_k, dim3((5*20*64+255)/256),  dim3(256), 0, stream, W_i, wif, 5, 147, 0);
  hipLaunchKernelGGL(conv_w_k, dim3((10*20*64+255)/256), dim3(256), 0, stream, W_h, whf, 10, 300, 0);
  hipLaunchKernelGGL(conv_w_k, dim3((14*20*64+255)/256), dim3(256), 0, stream, W_o, wof, 14, 433, 1);

  hipLaunchKernelGGL(mpnn_fused, dim3(MOLS), dim3(256), 0, stream,
                     f_atoms, f_bonds, a2b, b2a, b2revb,
                     wif, whf, wof, b_o, (float*)d_out);
}